// Round 11
// baseline (60.687 us; speedup 1.0000x reference)
//
#include <hip/hip_runtime.h>

typedef int i32x4 __attribute__((ext_vector_type(4)));

#define C_IN 128
#define HW 56
#define PIX 3136            // 56*56
#define NPLANE 401408       // 128*3136
#define PROWB 7424          // 58*128 bytes per padded row (i8)
#define APAD_NSTRIDE 430592 // 58*58*128

// direct global->LDS DMA, 16B per lane, linear dest (wave-uniform base + lane*16)
static __device__ __forceinline__ void gload_lds16(const void* g, void* l) {
  __builtin_amdgcn_global_load_lds((__attribute__((address_space(1))) unsigned int*)g,
                                   (__attribute__((address_space(3))) unsigned int*)l, 16, 0, 0);
}

// ---------------- fused stats: blocks 0..1023 = BN (c,slice), 1024..1087 = weight chunks ----------------
__global__ __launch_bounds__(256) void stats_k(const float* __restrict__ x,
                                               const float* __restrict__ w,
                                               double* __restrict__ bnpart,
                                               double* __restrict__ wpart) {
  const int b = blockIdx.x, tid = threadIdx.x;
  double s = 0.0, s2 = 0.0;
  if (b < 1024) {
    const int c = b & 127, sl = b >> 7;
    for (int n = sl * 4; n < sl * 4 + 4; ++n) {
      const float4* p = (const float4*)(x + (size_t)(n * C_IN + c) * PIX);
      for (int i = tid; i < PIX / 4; i += 256) {
        float4 v = p[i];
        s  += (double)v.x + (double)v.y + (double)v.z + (double)v.w;
        s2 += (double)v.x * v.x + (double)v.y * v.y + (double)v.z * v.z + (double)v.w * v.w;
      }
    }
  } else {
    const int wb = b - 1024;
    const float4* p = (const float4*)w;
    for (int i = wb * 576 + tid; i < (wb + 1) * 576; i += 256) {
      float4 v = p[i];
      s  += (double)v.x + (double)v.y + (double)v.z + (double)v.w;
      s2 += (double)v.x * v.x + (double)v.y * v.y + (double)v.z * v.z + (double)v.w * v.w;
    }
  }
  __shared__ double red[8];
  const int lane = tid & 63, wv = tid >> 6;
  for (int off = 32; off; off >>= 1) { s += __shfl_down(s, off); s2 += __shfl_down(s2, off); }
  if (lane == 0) { red[wv * 2] = s; red[wv * 2 + 1] = s2; }
  __syncthreads();
  if (tid == 0) {
    // bnpart layout [c][sl] (consumer reads c*8+sl)
    double* dst = (b < 1024) ? (bnpart + ((b & 127) * 8 + (b >> 7)) * 2)
                             : (wpart + (b - 1024) * 2);
    dst[0] = red[0] + red[2] + red[4] + red[6];
    dst[1] = red[1] + red[3] + red[5] + red[7];
  }
}

// ---------------- fused quantize: y<32 = act rows (pre-swizzled apad), y==32 = weights (LINEAR wq) ----------------
__global__ __launch_bounds__(256) void quant_k(const float* __restrict__ x,
                                               const float* __restrict__ w,
                                               const float* __restrict__ gamma,
                                               const float* __restrict__ beta,
                                               const double* __restrict__ bnpart,
                                               const double* __restrict__ wpart,
                                               signed char* __restrict__ apad,
                                               signed char* __restrict__ wq,
                                               float* __restrict__ stepp) {
  const int tid = threadIdx.x;
  if (blockIdx.y == 32) {
    // ---- weight path: block bx handles oc in {bx, bx+58, bx+116} ----
    const int bx = blockIdx.x;
    __shared__ float steps;
    __shared__ __align__(16) signed char wl[3 * 1152];   // [oi][rs][c]
    if (tid < 64) {
      double s = wpart[tid * 2], s2 = wpart[tid * 2 + 1];
      for (int off = 32; off; off >>= 1) { s += __shfl_down(s, off); s2 += __shfl_down(s2, off); }
      if (tid == 0) {
        const double mean = s / 147456.0;
        const double var = s2 / 147456.0 - mean * mean;
        steps = 0.996f * (float)sqrt(var);
        if (bx == 0) stepp[0] = steps;
      }
    }
    __syncthreads();
    const float step = steps;
    for (int i = tid; i < 3456; i += 256) {
      const int oi = i / 1152, rem = i - oi * 1152;
      const int oc = bx + oi * 58;
      if (oc < 128) {
        const int c = rem / 9, rs = rem - c * 9;
        const float v = w[(size_t)(oc * C_IN + c) * 9 + rs];
        float t = 2.f * rintf(v / step + 0.5f) - 1.f;  // iw2 odd ints
        t = fminf(fmaxf(t, -3.f), 3.f);
        wl[oi * 1152 + rs * 128 + c] = (signed char)(int)t;
      }
    }
    __syncthreads();
    for (int i = tid; i < 216; i += 256) {  // 3 oc * 9 rs * 8 uint4, LINEAR wq[rs][oc][c]
      const int oi = i / 72, rem = i - oi * 72;
      const int oc = bx + oi * 58;
      if (oc < 128) {
        const int rs = rem >> 3, c16 = rem & 7;
        *(uint4*)(wq + rs * 16384 + oc * 128 + c16 * 16) =
            *(const uint4*)(wl + oi * 1152 + rs * 128 + c16 * 16);
      }
    }
    return;
  }
  // ---- act path: padded row hh of image n ----
  const int hh = blockIdx.x;
  const int n = blockIdx.y;
  __shared__ float2 aff[128];
  __shared__ __align__(16) signed char lds[58 * 144];
  if (tid < 128) {
    double s = 0.0, s2 = 0.0;
    for (int i = 0; i < 8; ++i) { s += bnpart[(tid * 8 + i) * 2]; s2 += bnpart[(tid * 8 + i) * 2 + 1]; }
    const double mean = s / 100352.0;
    const double var = s2 / 100352.0 - mean * mean;
    const double inv = 1.0 / sqrt(var + 1e-3);
    aff[tid] = make_float2((float)((double)gamma[tid] * inv),
                           (float)((double)beta[tid] - mean * inv * (double)gamma[tid]));
  }
  uint4* lds4 = (uint4*)lds;
  for (int i = tid; i < 58 * 144 / 16; i += 256) lds4[i] = make_uint4(0, 0, 0, 0);
  __syncthreads();
  if (hh >= 1 && hh <= 56) {
    const float* xp = x + (size_t)n * NPLANE + (hh - 1) * HW;
    for (int i = tid; i < C_IN * HW; i += 256) {
      const int ww = i % HW, c = i / HW;
      const float v = xp[(size_t)c * PIX + ww];
      const float2 af = aff[c];
      const float xn = fmaf(v, af.x, af.y);
      const float y = fminf(fmaxf(xn, 0.f), 1.614f);          // clip [0, 3*0.538]
      lds[(ww + 1) * 144 + c] = (signed char)(int)rintf(y * (1.f / 0.538f));
    }
  }
  __syncthreads();
  signed char* dst = apad + (size_t)n * APAD_NSTRIDE;
  for (int i = tid; i < 58 * 8; i += 256) {
    const int col = i >> 3, c16 = i & 7;
    const int pp = hh * 58 + col;
    *(uint4*)(dst + (((size_t)pp * 128 + c16 * 16) ^ ((pp & 7) << 4))) = lds4[col * 9 + c16];
  }
}

// ---------------- conv: weights-in-registers; act LDS via DMA; ONE barrier; zero K-loop VMEM ----------------
// grid 896 = 32 n x 14 rg x 2 oc-halves; block = 64 oc x 224 px; wave = 32 oc x 112 px (of=2, pf=7).
__global__ __launch_bounds__(256, 2) void conv_k(const signed char* __restrict__ apad,
                                                 const signed char* __restrict__ wq,
                                                 const float* __restrict__ stepp,
                                                 float* __restrict__ out) {
  __shared__ __align__(16) signed char Al[45056];  // 6 padded rows x 58 x 128 (44544B used), XOR-swizzled
  // XCD-bijective swizzle: 896 = 8 XCDs x 112; consecutive vid share Al region (oh pair) and wq.
  const int bid = blockIdx.x;
  const int vid = (bid & 7) * 112 + (bid >> 3);
  const int n = vid / 28;
  const int rem = vid - n * 28;
  const int rg = rem >> 1;
  const int oh = rem & 1;
  const int tid = threadIdx.x;
  const int wv = tid >> 6, lane = tid & 63;
  const int lr = lane & 15, q4 = lane >> 4;
  const int kq = q4 * 16;
  const int ocb = oh * 64 + (wv & 1) * 32;   // this wave's 32-oc base
  const int phalf = (wv >> 1) * 112;

  // stage act: 44544 B = 43 full 1KB chunks + one half chunk (lanes 0..31)
  {
    const signed char* gsrc = apad + (size_t)n * APAD_NSTRIDE + (size_t)(rg * 4) * PROWB;
    for (int i = wv; i < 44; i += 4)
      if (i < 43 || lane < 32)
        gload_lds16(gsrc + i * 1024 + lane * 16, Al + i * 1024);
  }

  // W prologue: all 18 phases' A-fragments into registers (36 x 16B = 144 VGPR)
  i32x4 wreg[9][2][2];
  {
    const signed char* wb = wq + (ocb + lr) * 128 + kq;
#pragma unroll
    for (int rs = 0; rs < 9; ++rs)
#pragma unroll
      for (int k64 = 0; k64 < 2; ++k64)
#pragma unroll
        for (int of = 0; of < 2; ++of)
          wreg[rs][k64][of] = *(const i32x4*)(wb + rs * 16384 + of * 2048 + k64 * 64);
  }

  int pbase[7];
#pragma unroll
  for (int pf = 0; pf < 7; ++pf) {
    const int po = phalf + pf * 16 + lr;   // 0..223
    pbase[pf] = (po / 56) * 58 + po % 56;
  }

  i32x4 acc[7][2];
#pragma unroll
  for (int i = 0; i < 7; ++i) {
    acc[i][0] = (i32x4){0, 0, 0, 0};
    acc[i][1] = (i32x4){0, 0, 0, 0};
  }

  __syncthreads();  // Al ready (drains DMA + W loads); only barrier in the kernel

  // K-loop: pure ds_read + MFMA, 18 phases, no VMEM, no barriers
#pragma unroll
  for (int rs = 0; rs < 9; ++rs) {
    const int poff = (rs / 3) * 58 + (rs % 3);
#pragma unroll
    for (int k64 = 0; k64 < 2; ++k64) {
      const int kb = k64 * 64 + kq;
#pragma unroll
      for (int pf = 0; pf < 7; ++pf) {
        const int pp = pbase[pf] + poff;
        const i32x4 bf = *(const i32x4*)(Al + ((pp * 128 + kb) ^ ((pp & 7) << 4)));
        acc[pf][0] = __builtin_amdgcn_mfma_i32_16x16x64_i8(wreg[rs][k64][0], bf, acc[pf][0], 0, 0, 0);
        acc[pf][1] = __builtin_amdgcn_mfma_i32_16x16x64_i8(wreg[rs][k64][1], bf, acc[pf][1], 0, 0, 0);
      }
    }
  }

  const float oscale = 0.269f * stepp[0];  // a_step * w_step/2
  float* outn = out + (size_t)n * NPLANE + (size_t)rg * 224;  // 4-row slab base
#pragma unroll
  for (int pf = 0; pf < 7; ++pf) {
    const int po = phalf + pf * 16 + lr;
    float* op = outn + po;
#pragma unroll
    for (int of = 0; of < 2; ++of) {
      const int oc = ocb + of * 16 + q4 * 4;
#pragma unroll
      for (int q = 0; q < 4; ++q)
        op[(size_t)(oc + q) * PIX] = (float)acc[pf][of][q] * oscale;
    }
  }
}

extern "C" void kernel_launch(void* const* d_in, const int* in_sizes, int n_in,
                              void* d_out, int out_size, void* d_ws, size_t ws_size,
                              hipStream_t stream) {
  const float* x = (const float*)d_in[0];
  const float* gamma = (const float*)d_in[1];
  const float* beta = (const float*)d_in[2];
  const float* w = (const float*)d_in[3];
  float* out = (float*)d_out;
  char* ws = (char*)d_ws;

  double* bnpart = (double*)(ws);                  // 16384 B
  double* wpart = (double*)(ws + 16384);           // 1024 B
  float* stepp = (float*)(ws + 17408);             // 4 B
  signed char* wq = (signed char*)(ws + 18432);    // 9*128*128 = 147456 B
  signed char* apad = (signed char*)(ws + 196608); // 32*58*58*128 = 13778944 B

  stats_k<<<1088, 256, 0, stream>>>(x, w, bnpart, wpart);
  quant_k<<<dim3(58, 33), 256, 0, stream>>>(x, w, gamma, beta, bnpart, wpart, apad, wq, stepp);
  conv_k<<<896, 256, 0, stream>>>(apad, wq, stepp, out);
}

// Round 12
// 54.325 us; speedup vs baseline: 1.1171x; 1.1171x over previous
//
#include <hip/hip_runtime.h>

typedef int i32x4 __attribute__((ext_vector_type(4)));

#define C_IN 128
#define HW 56
#define PIX 3136            // 56*56
#define NPLANE 401408       // 128*3136
#define PROWB 7424          // 58*128 bytes per padded row (i8)
#define APAD_NSTRIDE 430592 // 58*58*128

// direct global->LDS DMA, 16B per lane, linear dest (wave-uniform base + lane*16)
static __device__ __forceinline__ void gload_lds16(const void* g, void* l) {
  __builtin_amdgcn_global_load_lds((__attribute__((address_space(1))) unsigned int*)g,
                                   (__attribute__((address_space(3))) unsigned int*)l, 16, 0, 0);
}

// ---------------- fused stats: blocks 0..1023 = BN (c,slice), 1024..1087 = weight chunks ----------------
__global__ __launch_bounds__(256) void stats_k(const float* __restrict__ x,
                                               const float* __restrict__ w,
                                               double* __restrict__ bnpart,
                                               double* __restrict__ wpart) {
  const int b = blockIdx.x, tid = threadIdx.x;
  double s = 0.0, s2 = 0.0;
  if (b < 1024) {
    const int c = b & 127, sl = b >> 7;
    for (int n = sl * 4; n < sl * 4 + 4; ++n) {
      const float4* p = (const float4*)(x + (size_t)(n * C_IN + c) * PIX);
      for (int i = tid; i < PIX / 4; i += 256) {
        float4 v = p[i];
        s  += (double)v.x + (double)v.y + (double)v.z + (double)v.w;
        s2 += (double)v.x * v.x + (double)v.y * v.y + (double)v.z * v.z + (double)v.w * v.w;
      }
    }
  } else {
    const int wb = b - 1024;
    const float4* p = (const float4*)w;
    for (int i = wb * 576 + tid; i < (wb + 1) * 576; i += 256) {
      float4 v = p[i];
      s  += (double)v.x + (double)v.y + (double)v.z + (double)v.w;
      s2 += (double)v.x * v.x + (double)v.y * v.y + (double)v.z * v.z + (double)v.w * v.w;
    }
  }
  __shared__ double red[8];
  const int lane = tid & 63, wv = tid >> 6;
  for (int off = 32; off; off >>= 1) { s += __shfl_down(s, off); s2 += __shfl_down(s2, off); }
  if (lane == 0) { red[wv * 2] = s; red[wv * 2 + 1] = s2; }
  __syncthreads();
  if (tid == 0) {
    // bnpart layout [c][sl] (consumer reads c*8+sl)
    double* dst = (b < 1024) ? (bnpart + ((b & 127) * 8 + (b >> 7)) * 2)
                             : (wpart + (b - 1024) * 2);
    dst[0] = red[0] + red[2] + red[4] + red[6];
    dst[1] = red[1] + red[3] + red[5] + red[7];
  }
}

// ---------------- fused quantize: y<32 = act rows (pre-swizzled apad), y==32 = weights (pre-swizzled wq) ----------------
__global__ __launch_bounds__(256) void quant_k(const float* __restrict__ x,
                                               const float* __restrict__ w,
                                               const float* __restrict__ gamma,
                                               const float* __restrict__ beta,
                                               const double* __restrict__ bnpart,
                                               const double* __restrict__ wpart,
                                               signed char* __restrict__ apad,
                                               signed char* __restrict__ wq,
                                               float* __restrict__ stepp) {
  const int tid = threadIdx.x;
  if (blockIdx.y == 32) {
    // ---- weight path: block bx handles oc in {bx, bx+58, bx+116} ----
    const int bx = blockIdx.x;
    __shared__ float steps;
    __shared__ __align__(16) signed char wl[3 * 1152];   // [oi][rs][c]
    if (tid < 64) {
      double s = wpart[tid * 2], s2 = wpart[tid * 2 + 1];
      for (int off = 32; off; off >>= 1) { s += __shfl_down(s, off); s2 += __shfl_down(s2, off); }
      if (tid == 0) {
        const double mean = s / 147456.0;
        const double var = s2 / 147456.0 - mean * mean;
        steps = 0.996f * (float)sqrt(var);
        if (bx == 0) stepp[0] = steps;
      }
    }
    __syncthreads();
    const float step = steps;
    for (int i = tid; i < 3456; i += 256) {
      const int oi = i / 1152, rem = i - oi * 1152;
      const int oc = bx + oi * 58;
      if (oc < 128) {
        const int c = rem / 9, rs = rem - c * 9;
        const float v = w[(size_t)(oc * C_IN + c) * 9 + rs];
        float t = 2.f * rintf(v / step + 0.5f) - 1.f;  // iw2 odd ints
        t = fminf(fmaxf(t, -3.f), 3.f);
        wl[oi * 1152 + rs * 128 + c] = (signed char)(int)t;
      }
    }
    __syncthreads();
    for (int i = tid; i < 216; i += 256) {  // 3 oc * 9 rs * 8 uint4, PRE-SWIZZLED wq[rs][oc^][c]
      const int oi = i / 72, rem = i - oi * 72;
      const int oc = bx + oi * 58;
      if (oc < 128) {
        const int rs = rem >> 3, c16 = rem & 7;
        *(uint4*)(wq + rs * 16384 + ((oc * 128 + c16 * 16) ^ ((oc & 7) << 4))) =
            *(const uint4*)(wl + oi * 1152 + rs * 128 + c16 * 16);
      }
    }
    return;
  }
  // ---- act path: padded row hh of image n ----
  const int hh = blockIdx.x;
  const int n = blockIdx.y;
  __shared__ float2 aff[128];
  __shared__ __align__(16) signed char lds[58 * 144];
  if (tid < 128) {
    double s = 0.0, s2 = 0.0;
    for (int i = 0; i < 8; ++i) { s += bnpart[(tid * 8 + i) * 2]; s2 += bnpart[(tid * 8 + i) * 2 + 1]; }
    const double mean = s / 100352.0;
    const double var = s2 / 100352.0 - mean * mean;
    const double inv = 1.0 / sqrt(var + 1e-3);
    aff[tid] = make_float2((float)((double)gamma[tid] * inv),
                           (float)((double)beta[tid] - mean * inv * (double)gamma[tid]));
  }
  uint4* lds4 = (uint4*)lds;
  for (int i = tid; i < 58 * 144 / 16; i += 256) lds4[i] = make_uint4(0, 0, 0, 0);
  __syncthreads();
  if (hh >= 1 && hh <= 56) {
    const float* xp = x + (size_t)n * NPLANE + (hh - 1) * HW;
    for (int i = tid; i < C_IN * HW; i += 256) {
      const int ww = i % HW, c = i / HW;
      const float v = xp[(size_t)c * PIX + ww];
      const float2 af = aff[c];
      const float xn = fmaf(v, af.x, af.y);
      const float y = fminf(fmaxf(xn, 0.f), 1.614f);          // clip [0, 3*0.538]
      lds[(ww + 1) * 144 + c] = (signed char)(int)rintf(y * (1.f / 0.538f));
    }
  }
  __syncthreads();
  signed char* dst = apad + (size_t)n * APAD_NSTRIDE;
  for (int i = tid; i < 58 * 8; i += 256) {
    const int col = i >> 3, c16 = i & 7;
    const int pp = hh * 58 + col;
    *(uint4*)(dst + (((size_t)pp * 128 + c16 * 16) ^ ((pp & 7) << 4))) = lds4[col * 9 + c16];
  }
}

// ---------------- conv: 128oc x 112px (2 rows); W triple-buffered, counted vmcnt, raw barriers ----------------
__global__ __launch_bounds__(256, 2) void conv_k(const signed char* __restrict__ apad,
                                                 const signed char* __restrict__ wq,
                                                 const float* __restrict__ stepp,
                                                 float* __restrict__ out) {
  __shared__ __align__(16) signed char Al[29696];     // 4 padded rows x 58 x 128 (pre-swizzled bytes)
  __shared__ __align__(16) signed char Wl[3][16384];  // weight panels, triple-buffered
  // XCD-bijective swizzle: 896 = 8 XCDs x 112; consecutive vid share apad halo + wq in one L2.
  const int bid = blockIdx.x;
  const int vid = (bid & 7) * 112 + (bid >> 3);
  const int n = vid / 28;
  const int rg = vid - n * 28;      // 0..27, 2 output rows each
  const int tid = threadIdx.x;
  const int wv = tid >> 6, lane = tid & 63;
  const int lr = lane & 15, q4 = lane >> 4;
  const int kq = q4 * 16;
  const int row0 = wv * 32 + lr;    // wave's oc rows: row0, row0+16
  const int wswz = (row0 & 7) << 4; // same for row0+16
  const int rgo = (rg & 1) << 2;    // global-pixel phase of this 2-row slab (116*rg mod 8)

  // prologue: issue Al (29 x 1KB) then panels 0,1 (4 chunks/wave each)
  {
    const signed char* gsrc = apad + (size_t)n * APAD_NSTRIDE + (size_t)(rg * 2) * PROWB;
    for (int i = wv; i < 29; i += 4)
      gload_lds16(gsrc + i * 1024 + lane * 16, Al + i * 1024);
#pragma unroll
    for (int i = 0; i < 4; ++i)
      gload_lds16(wq + (wv + i * 4) * 1024 + lane * 16, &Wl[0][(wv + i * 4) * 1024]);
#pragma unroll
    for (int i = 0; i < 4; ++i)
      gload_lds16(wq + 16384 + (wv + i * 4) * 1024 + lane * 16, &Wl[1][(wv + i * 4) * 1024]);
  }

  int pbase[7];
#pragma unroll
  for (int pf = 0; pf < 7; ++pf) {
    const int po = pf * 16 + lr;   // 0..111
    pbase[pf] = (po / 56) * 58 + po % 56;
  }

  i32x4 acc[7][2];
#pragma unroll
  for (int i = 0; i < 7; ++i) {
    acc[i][0] = (i32x4){0, 0, 0, 0};
    acc[i][1] = (i32x4){0, 0, 0, 0};
  }

  // Al + panel0 landed (panel1's 4 newest may fly); then barrier
  asm volatile("s_waitcnt vmcnt(4)" ::: "memory");
  __builtin_amdgcn_sched_barrier(0);
  __builtin_amdgcn_s_barrier();
  __builtin_amdgcn_sched_barrier(0);

#define ISSUE(P)                                                                      \
  {                                                                                   \
    const signed char* ws_ = wq + (P) * 16384;                                        \
    signed char* wd_ = Wl[(P) % 3];                                                   \
    _Pragma("unroll")                                                                 \
    for (int i = 0; i < 4; ++i)                                                       \
      gload_lds16(ws_ + (wv + i * 4) * 1024 + lane * 16, wd_ + (wv + i * 4) * 1024);  \
  }
#define COMP(RS)                                                                      \
  {                                                                                   \
    const signed char* Wb = Wl[(RS) % 3];                                             \
    constexpr int poff_ = ((RS) / 3) * 58 + ((RS) % 3);                               \
    _Pragma("unroll")                                                                 \
    for (int k64 = 0; k64 < 2; ++k64) {                                               \
      const int kb = k64 * 64 + kq;                                                   \
      const i32x4 wf0 = *(const i32x4*)(Wb + row0 * 128 + (kb ^ wswz));               \
      const i32x4 wf1 = *(const i32x4*)(Wb + (row0 + 16) * 128 + (kb ^ wswz));        \
      _Pragma("unroll")                                                               \
      for (int pf = 0; pf < 7; ++pf) {                                                \
        const int p = pbase[pf] + poff_;                                              \
        const i32x4 bf = *(const i32x4*)(Al + p * 128 + (kb ^ (((p + rgo) & 7) << 4)));\
        acc[pf][0] = __builtin_amdgcn_mfma_i32_16x16x64_i8(wf0, bf, acc[pf][0], 0, 0, 0); \
        acc[pf][1] = __builtin_amdgcn_mfma_i32_16x16x64_i8(wf1, bf, acc[pf][1], 0, 0, 0); \
      }                                                                               \
    }                                                                                 \
  }
#define WAITBAR(N)                                    \
  asm volatile("s_waitcnt vmcnt(" #N ")" ::: "memory"); \
  __builtin_amdgcn_sched_barrier(0);                  \
  __builtin_amdgcn_s_barrier();                       \
  __builtin_amdgcn_sched_barrier(0);

  ISSUE(2) COMP(0) WAITBAR(4)   // panel1 landed; panel2 in flight
  ISSUE(3) COMP(1) WAITBAR(4)
  ISSUE(4) COMP(2) WAITBAR(4)
  ISSUE(5) COMP(3) WAITBAR(4)
  ISSUE(6) COMP(4) WAITBAR(4)
  ISSUE(7) COMP(5) WAITBAR(4)
  ISSUE(8) COMP(6) WAITBAR(4)
           COMP(7) WAITBAR(0)   // drain: panel8 must be in
           COMP(8)
#undef ISSUE
#undef COMP
#undef WAITBAR

  const float oscale = 0.269f * stepp[0];  // a_step * w_step/2
  float* outn = out + (size_t)n * NPLANE + (size_t)rg * 112;  // 2-row slab base
#pragma unroll
  for (int pf = 0; pf < 7; ++pf) {
    const int po = pf * 16 + lr;
    float* op = outn + po;
#pragma unroll
    for (int of = 0; of < 2; ++of) {
      const int oc = wv * 32 + of * 16 + q4 * 4;
#pragma unroll
      for (int q = 0; q < 4; ++q)
        op[(size_t)(oc + q) * PIX] = (float)acc[pf][of][q] * oscale;
    }
  }
}

extern "C" void kernel_launch(void* const* d_in, const int* in_sizes, int n_in,
                              void* d_out, int out_size, void* d_ws, size_t ws_size,
                              hipStream_t stream) {
  const float* x = (const float*)d_in[0];
  const float* gamma = (const float*)d_in[1];
  const float* beta = (const float*)d_in[2];
  const float* w = (const float*)d_in[3];
  float* out = (float*)d_out;
  char* ws = (char*)d_ws;

  double* bnpart = (double*)(ws);                  // 16384 B
  double* wpart = (double*)(ws + 16384);           // 1024 B
  float* stepp = (float*)(ws + 17408);             // 4 B
  signed char* wq = (signed char*)(ws + 18432);    // 9*128*128 = 147456 B
  signed char* apad = (signed char*)(ws + 196608); // 32*58*58*128 = 13778944 B

  stats_k<<<1088, 256, 0, stream>>>(x, w, bnpart, wpart);
  quant_k<<<dim3(58, 33), 256, 0, stream>>>(x, w, gamma, beta, bnpart, wpart, apad, wq, stepp);
  conv_k<<<896, 256, 0, stream>>>(apad, wq, stepp, out);
}

// Round 13
// 53.767 us; speedup vs baseline: 1.1287x; 1.0104x over previous
//
#include <hip/hip_runtime.h>

typedef int i32x4 __attribute__((ext_vector_type(4)));

#define C_IN 128
#define HW 56
#define PIX 3136            // 56*56
#define NPLANE 401408       // 128*3136
#define PROWB 7424          // 58*128 bytes per padded row (i8)
#define APAD_NSTRIDE 430592 // 58*58*128

// direct global->LDS DMA, 16B per lane, linear dest (wave-uniform base + lane*16)
static __device__ __forceinline__ void gload_lds16(const void* g, void* l) {
  __builtin_amdgcn_global_load_lds((__attribute__((address_space(1))) unsigned int*)g,
                                   (__attribute__((address_space(3))) unsigned int*)l, 16, 0, 0);
}

// ---------------- fused stats: blocks 0..1023 = BN (c,slice), 1024..1087 = weight chunks ----------------
__global__ __launch_bounds__(256) void stats_k(const float* __restrict__ x,
                                               const float* __restrict__ w,
                                               double* __restrict__ bnpart,
                                               double* __restrict__ wpart) {
  const int b = blockIdx.x, tid = threadIdx.x;
  double s = 0.0, s2 = 0.0;
  if (b < 1024) {
    const int c = b & 127, sl = b >> 7;
    for (int n = sl * 4; n < sl * 4 + 4; ++n) {
      const float4* p = (const float4*)(x + (size_t)(n * C_IN + c) * PIX);
      for (int i = tid; i < PIX / 4; i += 256) {
        float4 v = p[i];
        s  += (double)v.x + (double)v.y + (double)v.z + (double)v.w;
        s2 += (double)v.x * v.x + (double)v.y * v.y + (double)v.z * v.z + (double)v.w * v.w;
      }
    }
  } else {
    const int wb = b - 1024;
    const float4* p = (const float4*)w;
    for (int i = wb * 576 + tid; i < (wb + 1) * 576; i += 256) {
      float4 v = p[i];
      s  += (double)v.x + (double)v.y + (double)v.z + (double)v.w;
      s2 += (double)v.x * v.x + (double)v.y * v.y + (double)v.z * v.z + (double)v.w * v.w;
    }
  }
  __shared__ double red[8];
  const int lane = tid & 63, wv = tid >> 6;
  for (int off = 32; off; off >>= 1) { s += __shfl_down(s, off); s2 += __shfl_down(s2, off); }
  if (lane == 0) { red[wv * 2] = s; red[wv * 2 + 1] = s2; }
  __syncthreads();
  if (tid == 0) {
    // bnpart layout [c][sl] (consumer reads c*8+sl)
    double* dst = (b < 1024) ? (bnpart + ((b & 127) * 8 + (b >> 7)) * 2)
                             : (wpart + (b - 1024) * 2);
    dst[0] = red[0] + red[2] + red[4] + red[6];
    dst[1] = red[1] + red[3] + red[5] + red[7];
  }
}

// ---------------- fused quantize: y<32 = act rows (pre-swizzled apad), y==32 = weights (pre-swizzled wq) ----------------
__global__ __launch_bounds__(256) void quant_k(const float* __restrict__ x,
                                               const float* __restrict__ w,
                                               const float* __restrict__ gamma,
                                               const float* __restrict__ beta,
                                               const double* __restrict__ bnpart,
                                               const double* __restrict__ wpart,
                                               signed char* __restrict__ apad,
                                               signed char* __restrict__ wq,
                                               float* __restrict__ stepp) {
  const int tid = threadIdx.x;
  if (blockIdx.y == 32) {
    // ---- weight path: block bx handles oc in {bx, bx+58, bx+116} ----
    const int bx = blockIdx.x;
    __shared__ float steps;
    __shared__ __align__(16) signed char wl[3 * 1152];   // [oi][rs][c]
    if (tid < 64) {
      double s = wpart[tid * 2], s2 = wpart[tid * 2 + 1];
      for (int off = 32; off; off >>= 1) { s += __shfl_down(s, off); s2 += __shfl_down(s2, off); }
      if (tid == 0) {
        const double mean = s / 147456.0;
        const double var = s2 / 147456.0 - mean * mean;
        steps = 0.996f * (float)sqrt(var);
        if (bx == 0) stepp[0] = steps;
      }
    }
    __syncthreads();
    const float step = steps;
    for (int i = tid; i < 3456; i += 256) {
      const int oi = i / 1152, rem = i - oi * 1152;
      const int oc = bx + oi * 58;
      if (oc < 128) {
        const int c = rem / 9, rs = rem - c * 9;
        const float v = w[(size_t)(oc * C_IN + c) * 9 + rs];
        float t = 2.f * rintf(v / step + 0.5f) - 1.f;  // iw2 odd ints
        t = fminf(fmaxf(t, -3.f), 3.f);
        wl[oi * 1152 + rs * 128 + c] = (signed char)(int)t;
      }
    }
    __syncthreads();
    for (int i = tid; i < 216; i += 256) {  // 3 oc * 9 rs * 8 uint4, PRE-SWIZZLED wq[rs][oc^][c]
      const int oi = i / 72, rem = i - oi * 72;
      const int oc = bx + oi * 58;
      if (oc < 128) {
        const int rs = rem >> 3, c16 = rem & 7;
        *(uint4*)(wq + rs * 16384 + ((oc * 128 + c16 * 16) ^ ((oc & 7) << 4))) =
            *(const uint4*)(wl + oi * 1152 + rs * 128 + c16 * 16);
      }
    }
    return;
  }
  // ---- act path: padded row hh of image n ----
  const int hh = blockIdx.x;
  const int n = blockIdx.y;
  __shared__ float2 aff[128];
  __shared__ __align__(16) signed char lds[58 * 144];
  if (tid < 128) {
    double s = 0.0, s2 = 0.0;
    for (int i = 0; i < 8; ++i) { s += bnpart[(tid * 8 + i) * 2]; s2 += bnpart[(tid * 8 + i) * 2 + 1]; }
    const double mean = s / 100352.0;
    const double var = s2 / 100352.0 - mean * mean;
    const double inv = 1.0 / sqrt(var + 1e-3);
    aff[tid] = make_float2((float)((double)gamma[tid] * inv),
                           (float)((double)beta[tid] - mean * inv * (double)gamma[tid]));
  }
  uint4* lds4 = (uint4*)lds;
  for (int i = tid; i < 58 * 144 / 16; i += 256) lds4[i] = make_uint4(0, 0, 0, 0);
  __syncthreads();
  if (hh >= 1 && hh <= 56) {
    const float* xp = x + (size_t)n * NPLANE + (hh - 1) * HW;
    for (int i = tid; i < C_IN * HW; i += 256) {
      const int ww = i % HW, c = i / HW;
      const float v = xp[(size_t)c * PIX + ww];
      const float2 af = aff[c];
      const float xn = fmaf(v, af.x, af.y);
      const float y = fminf(fmaxf(xn, 0.f), 1.614f);          // clip [0, 3*0.538]
      lds[(ww + 1) * 144 + c] = (signed char)(int)rintf(y * (1.f / 0.538f));
    }
  }
  __syncthreads();
  signed char* dst = apad + (size_t)n * APAD_NSTRIDE;
  for (int i = tid; i < 58 * 8; i += 256) {
    const int col = i >> 3, c16 = i & 7;
    const int pp = hh * 58 + col;
    *(uint4*)(dst + (((size_t)pp * 128 + c16 * 16) ^ ((pp & 7) << 4))) = lds4[col * 9 + c16];
  }
}

// ---------------- conv: block = 128 oc x 224 px (4 rows); 4 waves; 2 blocks/CU ----------------
// r6 base + upfront fragment loads (burst ds_read -> MFMA cluster) + setprio.
__global__ __launch_bounds__(256, 2) void conv_k(const signed char* __restrict__ apad,
                                                 const signed char* __restrict__ wq,
                                                 const float* __restrict__ stepp,
                                                 float* __restrict__ out) {
  __shared__ __align__(16) signed char Al[45056];      // 6 padded rows x 58 x 128 (44544B used), XOR-swizzled
  __shared__ __align__(16) signed char Wl[2][16384];   // per-rs weight panel, double-buffered
  // XCD-bijective swizzle: 448 = 8 XCDs x 56.
  const int bid = blockIdx.x;
  const int vid = (bid & 7) * 56 + (bid >> 3);
  const int n = vid / 14;
  const int rg = vid - n * 14;
  const int tid = threadIdx.x;
  const int wv = tid >> 6, lane = tid & 63;
  const int lr = lane & 15, q4 = lane >> 4;
  const int kq = q4 * 16;
  const int ohalf = (wv & 1) * 64;
  const int phalf = (wv >> 1) * 112;

  // issue act stage: 44 x 1KB (43 full + half chunk)
  {
    const signed char* gsrc = apad + (size_t)n * APAD_NSTRIDE + (size_t)(rg * 4) * PROWB;
    for (int i = wv; i < 44; i += 4)
      if (i < 43 || lane < 32)
        gload_lds16(gsrc + i * 1024 + lane * 16, Al + i * 1024);
  }
  // issue W[rs=0]
  for (int i = wv; i < 16; i += 4)
    gload_lds16(wq + i * 1024 + lane * 16, &Wl[0][i * 1024]);

  int pbase[7];
#pragma unroll
  for (int pf = 0; pf < 7; ++pf) {
    const int po = phalf + pf * 16 + lr;   // 0..223
    pbase[pf] = (po / 56) * 58 + po % 56;
  }

  i32x4 acc[7][4];
#pragma unroll
  for (int i = 0; i < 7; ++i)
#pragma unroll
    for (int j = 0; j < 4; ++j) acc[i][j] = (i32x4){0, 0, 0, 0};

  __syncthreads();  // drains all staging loads

  for (int rs = 0; rs < 9; ++rs) {
    if (rs < 8) {  // prefetch next weight panel into the other buffer
      for (int i = wv; i < 16; i += 4)
        gload_lds16(wq + (rs + 1) * 16384 + i * 1024 + lane * 16, &Wl[(rs + 1) & 1][i * 1024]);
    }
    const int r = rs / 3, s = rs - 3 * r;
    const int poff = r * 58 + s;
    const signed char* Wb = Wl[rs & 1];

    // ---- load ALL fragments of this phase upfront (burst of 22 ds_reads) ----
    i32x4 wf[2][4];
#pragma unroll
    for (int k64 = 0; k64 < 2; ++k64) {
      const int kb = k64 * 64 + kq;
#pragma unroll
      for (int of = 0; of < 4; ++of) {
        const int row = ohalf + of * 16 + lr;
        wf[k64][of] = *(const i32x4*)(Wb + row * 128 + (kb ^ ((row & 7) << 4)));
      }
    }
    i32x4 bf[2][7];
#pragma unroll
    for (int k64 = 0; k64 < 2; ++k64) {
      const int kb = k64 * 64 + kq;
#pragma unroll
      for (int pf = 0; pf < 7; ++pf) {
        const int p = pbase[pf] + poff;
        bf[k64][pf] = *(const i32x4*)(Al + p * 128 + (kb ^ ((p & 7) << 4)));
      }
    }

    // ---- MFMA cluster (56) ----
    __builtin_amdgcn_s_setprio(1);
#pragma unroll
    for (int k64 = 0; k64 < 2; ++k64)
#pragma unroll
      for (int pf = 0; pf < 7; ++pf) {
        acc[pf][0] = __builtin_amdgcn_mfma_i32_16x16x64_i8(wf[k64][0], bf[k64][pf], acc[pf][0], 0, 0, 0);
        acc[pf][1] = __builtin_amdgcn_mfma_i32_16x16x64_i8(wf[k64][1], bf[k64][pf], acc[pf][1], 0, 0, 0);
        acc[pf][2] = __builtin_amdgcn_mfma_i32_16x16x64_i8(wf[k64][2], bf[k64][pf], acc[pf][2], 0, 0, 0);
        acc[pf][3] = __builtin_amdgcn_mfma_i32_16x16x64_i8(wf[k64][3], bf[k64][pf], acc[pf][3], 0, 0, 0);
      }
    __builtin_amdgcn_s_setprio(0);

    if (rs < 8) __syncthreads();  // all waves done with Wb; next panel landed
  }

  const float oscale = 0.269f * stepp[0];  // a_step * w_step/2
  float* outn = out + (size_t)n * NPLANE + (size_t)rg * 224;  // 4-row slab base
#pragma unroll
  for (int pf = 0; pf < 7; ++pf) {
    const int po = phalf + pf * 16 + lr;  // offset within slab = row*56+col
    float* op = outn + po;
#pragma unroll
    for (int of = 0; of < 4; ++of) {
      const int oc = ohalf + of * 16 + q4 * 4;
#pragma unroll
      for (int q = 0; q < 4; ++q)
        op[(size_t)(oc + q) * PIX] = (float)acc[pf][of][q] * oscale;
    }
  }
}

extern "C" void kernel_launch(void* const* d_in, const int* in_sizes, int n_in,
                              void* d_out, int out_size, void* d_ws, size_t ws_size,
                              hipStream_t stream) {
  const float* x = (const float*)d_in[0];
  const float* gamma = (const float*)d_in[1];
  const float* beta = (const float*)d_in[2];
  const float* w = (const float*)d_in[3];
  float* out = (float*)d_out;
  char* ws = (char*)d_ws;

  double* bnpart = (double*)(ws);                  // 16384 B
  double* wpart = (double*)(ws + 16384);           // 1024 B
  float* stepp = (float*)(ws + 17408);             // 4 B
  signed char* wq = (signed char*)(ws + 18432);    // 9*128*128 = 147456 B
  signed char* apad = (signed char*)(ws + 196608); // 32*58*58*128 = 13778944 B

  stats_k<<<1088, 256, 0, stream>>>(x, w, bnpart, wpart);
  quant_k<<<dim3(58, 33), 256, 0, stream>>>(x, w, gamma, beta, bnpart, wpart, apad, wq, stepp);
  conv_k<<<448, 256, 0, stream>>>(apad, wq, stepp, out);
}